// Round 10
// baseline (172.875 us; speedup 1.0000x reference)
//
#include <hip/hip_runtime.h>
#include <math.h>
#include <stdint.h>

// EKF batch step, N independent 5-state filters.
// Exploits A rows 3,4 == 0 => P_ has zero cross blocks, S diagonal,
// K has only 2 nonzeros.
//
// R10 = R9 + __launch_bounds__(256, 2).
// R8/R9 post-mortem: VGPR_Count=64 with ~110 VGPRs of live state (2x 34-reg
// Pref prefetch sets) => allocator spilled the prefetch buffers to scratch.
// Scratch is HBM-backed: predicted spill traffic (~68MB W + ~68MB R per
// dispatch) matches the observed +55MB WRITE / +27MB FETCH inflation, and
// the per-iteration scratch round-trip explains 64us @ 4.4% VALUBusy.
// launch_bounds(256,2) caps occupancy pressure => VGPR budget 256, no spill.

#define BLK 64          // items per wave-tile
#define SLICE_F 2560    // floats per wave slice (10 KiB)
// IN layout  (floats, within slice): P [0,1600) | x [1600,1920)
// OUT layout (floats, within slice): x [0,320) | P [320,1920) | K [1920,2560)

struct Pref {
    float4 p0, p1, p2, p3, p4, p5;  // P floats [0,1536), lane-coalesced
    float  pr;                      // P floats [1536,1600)
    float4 x4;                      // x floats [0,256)
    float  xr;                      // x floats [256,320)
    float2 av;                      // a pair of OWN item (direct use)
    float  y0, y1;                  // Y of OWN item (direct use)
};

__device__ __forceinline__ void load_pref(Pref& r,
    const float* __restrict__ Pg, const float* __restrict__ xg,
    const float* __restrict__ ag, const float* __restrict__ Yg,
    int N, int base, int l) {
    const float4* p4 = (const float4*)(Pg + (size_t)base * 25);
    r.p0 = p4[0 * 64 + l]; r.p1 = p4[1 * 64 + l]; r.p2 = p4[2 * 64 + l];
    r.p3 = p4[3 * 64 + l]; r.p4 = p4[4 * 64 + l]; r.p5 = p4[5 * 64 + l];
    r.pr = (Pg + (size_t)base * 25)[1536 + l];
    r.x4 = ((const float4*)(xg + (size_t)base * 5))[l];
    r.xr = (xg + (size_t)base * 5)[256 + l];
    r.av = ((const float2*)(ag + (size_t)base * 2))[l];
    r.y0 = Yg[base + l];
    r.y1 = Yg[N + base + l];
}

__device__ __forceinline__ void stage_write(const Pref& r, float* s, int l) {
    float4* s4 = (float4*)s;
    s4[0 * 64 + l] = r.p0; s4[1 * 64 + l] = r.p1; s4[2 * 64 + l] = r.p2;
    s4[3 * 64 + l] = r.p3; s4[4 * 64 + l] = r.p4; s4[5 * 64 + l] = r.p5;
    s[1536 + l] = r.pr;
    ((float4*)(s + 1600))[l] = r.x4;
    s[1856 + l] = r.xr;
}

struct EkfOut {
    float px, py, ang, xn3, xn4;
    float t00, s01, s02, t11, s12, t22, Pn33, Pn44;
    float K30, K41;
};

__device__ __forceinline__ EkfOut ekf_math(
    float x0, float x1, float x2, float a0, float a1, float y0, float y1,
    float p00, float p01, float p02, float p10, float p11, float p12,
    float p20, float p21, float p22,
    float g0, float g1, float og0, float og1,
    float q0, float q1, float q2, float q3, float q4,
    float e2s0, float e2s1, float e2k0, float e2k1)
{
    const float dt = 0.1f;
    const float fPI  = 3.14159265358979323846f;
    const float f2PI = 6.28318530717958647692f;
    const float EPS_ = 1e-6f;

    float vel = g0 * a0, angvel = g1 * a1;

    float ar = x2 + angvel * dt + fPI;
    float w = fmodf(ar, f2PI);
    if (w < 0.0f) w += f2PI;
    float ang = w - fPI;

    float s, c;
    sincosf(ang, &s, &c);

    EkfOut o;
    o.px = fminf(fmaxf(x0 + vel * c * dt, -1.0f), 1.0f);
    o.py = fminf(fmaxf(x1 + vel * s * dt, -1.0f), 1.0f);
    o.ang = ang;

    float m0 = -vel * s * dt, m1 = vel * c * dt;

    float b00 = p00 + m0 * p20, b01 = p01 + m0 * p21, b02 = p02 + m0 * p22;
    float b10 = p10 + m1 * p20, b11 = p11 + m1 * p21, b12 = p12 + m1 * p22;
    float t00 = b00 + m0 * b02, t01 = b01 + m1 * b02;
    float t10 = b10 + m0 * b12, t11 = b11 + m1 * b12;
    float t20 = p20 + m0 * p22, t21 = p21 + m1 * p22, t22 = p22;
    float t02 = b02, t12 = b12;

    t00 += q0; t11 += q1; t22 += q2;
    o.s01 = 0.5f * (t01 + t10);
    o.s02 = 0.5f * (t02 + t20);
    o.s12 = 0.5f * (t12 + t21);
    o.t00 = t00 + EPS_; o.t11 = t11 + EPS_; o.t22 = t22 + EPS_;

    float S00 = q3 * og0 * og0 + vel * vel * e2k0 + e2s0;
    float S11 = q4 * og1 * og1 + angvel * angvel * e2k1 + e2s1;
    o.K30 = q3 * og0 / S00;
    o.K41 = q4 * og1 / S11;

    o.xn3 = vel    + o.K30 * (y0 - og0 * vel);
    o.xn4 = angvel + o.K41 * (y1 - og1 * angvel);
    o.Pn33 = (1.0f - o.K30 * og0) * q3 + EPS_;
    o.Pn44 = (1.0f - o.K41 * og1) * q4 + EPS_;
    return o;
}

__global__ __launch_bounds__(256, 2) void ekf_kernel(
    const float* __restrict__ xg, const float* __restrict__ Pg,
    const float* __restrict__ ag, const float* __restrict__ Yg,
    const float* __restrict__ n1, const float* __restrict__ n2s,
    const float* __restrict__ n2k, const float* __restrict__ gains,
    const float* __restrict__ og, float* __restrict__ out, int N)
{
    // 4 independent wave slices; float4 array for 16B alignment.
    __shared__ float4 ldsv[4 * (SLICE_F / 4)];
    const int tid = threadIdx.x;
    const int wv = tid >> 6, l = tid & 63;
    float* s = (float*)ldsv + wv * SLICE_F;

    const int tiles = (N + BLK - 1) / BLK;
    const int NW = gridDim.x * 4;                // total wave-pipelines
    const int wp = blockIdx.x * 4 + wv;
    // CYCLIC: pipeline wp handles tiles wp, wp+NW, wp+2NW, ...
    const int myTiles = (wp < tiles) ? (tiles - wp + NW - 1) / NW : 0;
    if (myTiles <= 0) return;

    // Uniform scalars + transcendentals, once per wave.
    const float g0 = gains[0], g1 = gains[1];
    const float og0 = og[0], og1 = og[1];
    const float q0 = expf(2.f * n1[0]), q1 = expf(2.f * n1[1]),
                q2 = expf(2.f * n1[2]), q3 = expf(2.f * n1[3]),
                q4 = expf(2.f * n1[4]);
    const float e2s0 = expf(2.f * n2s[0]), e2s1 = expf(2.f * n2s[1]);
    const float e2k0 = expf(2.f * n2k[0]), e2k1 = expf(2.f * n2k[1]);

    Pref A, B;
    {   // prologue prefetch of first tile (if full)
        int b0 = wp * BLK;
        if (b0 + BLK <= N) load_pref(A, Pg, xg, ag, Yg, N, b0, l);
    }

    int k = 0;
    auto process = [&](Pref& cur, Pref& nxt) {
        const int base = (wp + k * NW) * BLK;
        if (base + BLK <= N) {
            // 1) stage tile k regs -> LDS (compiler waits counted vmcnt for
            //    cur's loads, issued one iteration ago).
            stage_write(cur, s, l);
            // 2) issue prefetch of tile k+1 (never the tail).
            if (k + 1 < myTiles) {
                int nb = (wp + (k + 1) * NW) * BLK;
                if (nb + BLK <= N) load_pref(nxt, Pg, xg, ag, Yg, N, nb, l);
            }
            // 3) read own slice (stride-25/5: odd stride => 2-way bank
            //    aliasing only, free). Same-wave DS ops are in-order => no
            //    barrier needed between stage_write and these reads.
            const float* pr = s + l * 25;
            float p00 = pr[0], p01 = pr[1], p02 = pr[2];
            float p10 = pr[5], p11 = pr[6], p12 = pr[7];
            float p20 = pr[10], p21 = pr[11], p22 = pr[12];
            const float* xr = s + 1600 + l * 5;
            float x0 = xr[0], x1 = xr[1], x2 = xr[2];

            EkfOut o = ekf_math(x0, x1, x2, cur.av.x, cur.av.y, cur.y0, cur.y1,
                                p00, p01, p02, p10, p11, p12, p20, p21, p22,
                                g0, g1, og0, og1, q0, q1, q2, q3, q4,
                                e2s0, e2s1, e2k0, e2k1);

            // 4) OUT layout (aliases IN; IN already consumed). Full writes
            //    incl. zeros (can't pre-init: aliased buffer).
            float* xx = s + l * 5;
            xx[0] = o.px; xx[1] = o.py; xx[2] = o.ang; xx[3] = o.xn3; xx[4] = o.xn4;
            float* pp = s + 320 + l * 25;
            pp[0]  = o.t00; pp[1]  = o.s01; pp[2]  = o.s02; pp[3]  = 0.f; pp[4]  = 0.f;
            pp[5]  = o.s01; pp[6]  = o.t11; pp[7]  = o.s12; pp[8]  = 0.f; pp[9]  = 0.f;
            pp[10] = o.s02; pp[11] = o.s12; pp[12] = o.t22; pp[13] = 0.f; pp[14] = 0.f;
            pp[15] = 0.f;   pp[16] = 0.f;   pp[17] = 0.f;   pp[18] = o.Pn33; pp[19] = 0.f;
            pp[20] = 0.f;   pp[21] = 0.f;   pp[22] = 0.f;   pp[23] = 0.f;   pp[24] = o.Pn44;
            float* kk = s + 1920 + l * 10;
            kk[0] = 0.f; kk[1] = 0.f; kk[2] = 0.f; kk[3] = 0.f; kk[4] = 0.f;
            kk[5] = 0.f; kk[6] = o.K30; kk[7] = 0.f; kk[8] = 0.f; kk[9] = o.K41;

            // 5) coalesced stores: 12 dwordx4 per wave.
            float4* gx4 = (float4*)(out + (size_t)base * 5);
            float4* gp4 = (float4*)(out + (size_t)5 * N + (size_t)base * 25);
            float4* gk4 = (float4*)(out + (size_t)30 * N + (size_t)base * 10);
            const float4* lx4 = (const float4*)s;
            const float4* lp4 = (const float4*)(s + 320);
            const float4* lk4 = (const float4*)(s + 1920);
            gx4[l] = lx4[l];
            if (l < 16) gx4[64 + l] = lx4[64 + l];
            #pragma unroll
            for (int j = 0; j < 6; ++j) gp4[j * 64 + l] = lp4[j * 64 + l];
            if (l < 16) gp4[384 + l] = lp4[384 + l];
            #pragma unroll
            for (int j = 0; j < 2; ++j) gk4[j * 64 + l] = lk4[j * 64 + l];
            if (l < 32) gk4[128 + l] = lk4[128 + l];
        } else {
            // Tail tile (global last, valid < 64): direct guarded path.
            const int i = base + l;
            if (i < N) {
                const float* pr = Pg + (size_t)i * 25;
                EkfOut o = ekf_math(xg[i * 5 + 0], xg[i * 5 + 1], xg[i * 5 + 2],
                                    ag[i * 2 + 0], ag[i * 2 + 1],
                                    Yg[i], Yg[N + i],
                                    pr[0], pr[1], pr[2], pr[5], pr[6], pr[7],
                                    pr[10], pr[11], pr[12],
                                    g0, g1, og0, og1, q0, q1, q2, q3, q4,
                                    e2s0, e2s1, e2k0, e2k1);
                float* gx = out + (size_t)i * 5;
                gx[0] = o.px; gx[1] = o.py; gx[2] = o.ang; gx[3] = o.xn3; gx[4] = o.xn4;
                float* gp = out + (size_t)5 * N + (size_t)i * 25;
                gp[0] = o.t00; gp[1] = o.s01; gp[2] = o.s02; gp[3] = 0.f; gp[4] = 0.f;
                gp[5] = o.s01; gp[6] = o.t11; gp[7] = o.s12; gp[8] = 0.f; gp[9] = 0.f;
                gp[10] = o.s02; gp[11] = o.s12; gp[12] = o.t22; gp[13] = 0.f; gp[14] = 0.f;
                gp[15] = 0.f; gp[16] = 0.f; gp[17] = 0.f; gp[18] = o.Pn33; gp[19] = 0.f;
                gp[20] = 0.f; gp[21] = 0.f; gp[22] = 0.f; gp[23] = 0.f; gp[24] = o.Pn44;
                float* gk = out + (size_t)30 * N + (size_t)i * 10;
                gk[0] = 0.f; gk[1] = 0.f; gk[2] = 0.f; gk[3] = 0.f; gk[4] = 0.f;
                gk[5] = 0.f; gk[6] = o.K30; gk[7] = 0.f; gk[8] = 0.f; gk[9] = o.K41;
            }
        }
    };

    // Ping-pong over two named register sets (no runtime-indexed arrays).
    while (true) {
        process(A, B);
        if (++k >= myTiles) break;
        process(B, A);
        if (++k >= myTiles) break;
    }
}

extern "C" void kernel_launch(void* const* d_in, const int* in_sizes, int n_in,
                              void* d_out, int out_size, void* d_ws, size_t ws_size,
                              hipStream_t stream) {
    const float* x     = (const float*)d_in[0];
    const float* P     = (const float*)d_in[1];
    const float* a     = (const float*)d_in[2];
    const float* Y     = (const float*)d_in[3];
    const float* n1    = (const float*)d_in[4];
    const float* n2s   = (const float*)d_in[5];
    const float* n2k   = (const float*)d_in[6];
    const float* gains = (const float*)d_in[7];
    const float* og    = (const float*)d_in[8];
    const int N = in_sizes[0] / 5;
    const int tiles = (N + BLK - 1) / BLK;
    int G = 768;          // 3 blocks/CU (40.96KB LDS) = 12 wave-pipelines/CU
    if (G * 4 > tiles) G = (tiles + 3) / 4;
    ekf_kernel<<<G, 256, 0, stream>>>(x, P, a, Y, n1, n2s, n2k, gains, og,
                                      (float*)d_out, N);
}

// Round 11
// 148.701 us; speedup vs baseline: 1.1626x; 1.1626x over previous
//
#include <hip/hip_runtime.h>
#include <math.h>
#include <stdint.h>

// EKF batch step, N independent 5-state filters.
// Exploits A rows 3,4 == 0 => P_ has zero cross blocks, S diagonal,
// K has only 2 nonzeros.
//
// R11: one-shot kernel, straight-line SSA, TLP-for-latency.
// R8-R10 post-mortem: the ping-pong Pref structs passed BY REFERENCE into
// the process() lambda were address-taken -> scratch-allocated (VGPR=60
// with a 256 budget proves it wasn't pressure). Spill arithmetic matched
// WRITE excess exactly (28 floats/lane/tile = 7KiB/tile * 7812 = 54,684KiB).
// Fix: no persistence, no prefetch, no structs, no lambdas. 256-thr blocks
// = 4 independent wave-tiles; 1954 blocks (under the ~166wg/us CP ceiling
// that pinned R1/R2/R4 at 47us); 11 independent named loads per wave give
// the MLP; 16 resident waves/CU give the TLP.

#define BLK 64          // items per wave-tile
#define SLICE_F 2560    // floats per wave LDS slice (10 KiB)
// IN layout  (floats, within slice): P [0,1600) | x [1600,1920)
// OUT layout (floats, within slice): x [0,320) | P [320,1920) | K [1920,2560)

__global__ __launch_bounds__(256) void ekf_kernel(
    const float* __restrict__ xg, const float* __restrict__ Pg,
    const float* __restrict__ ag, const float* __restrict__ Yg,
    const float* __restrict__ n1, const float* __restrict__ n2s,
    const float* __restrict__ n2k, const float* __restrict__ gains,
    const float* __restrict__ og, float* __restrict__ out, int N)
{
    __shared__ float4 ldsv[4 * (SLICE_F / 4)];   // 40 KiB -> 4 blocks/CU
    const int tid = threadIdx.x;
    const int wv = tid >> 6, l = tid & 63;
    float* s = (float*)ldsv + wv * SLICE_F;

    const int tiles = (N + BLK - 1) / BLK;
    const int tile = blockIdx.x * 4 + wv;
    if (tile >= tiles) return;
    const int base = tile * BLK;

    const float dt = 0.1f;
    const float fPI  = 3.14159265358979323846f;
    const float f2PI = 6.28318530717958647692f;
    const float EPS_ = 1e-6f;

    // Uniform scalars + transcendentals (SALU/VALU, overlap with loads).
    const float g0 = gains[0], g1 = gains[1];
    const float og0 = og[0], og1 = og[1];
    const float q0 = expf(2.f * n1[0]), q1 = expf(2.f * n1[1]),
                q2 = expf(2.f * n1[2]), q3 = expf(2.f * n1[3]),
                q4 = expf(2.f * n1[4]);
    const float e2s0 = expf(2.f * n2s[0]), e2s1 = expf(2.f * n2s[1]);
    const float e2k0 = expf(2.f * n2k[0]), e2k1 = expf(2.f * n2k[1]);

    if (base + BLK <= N) {
        // ---- 1) 11 independent coalesced loads into named SSA locals ----
        const float4* p4 = (const float4*)(Pg + (size_t)base * 25);
        float4 v0 = p4[0 * 64 + l];
        float4 v1 = p4[1 * 64 + l];
        float4 v2 = p4[2 * 64 + l];
        float4 v3 = p4[3 * 64 + l];
        float4 v4 = p4[4 * 64 + l];
        float4 v5 = p4[5 * 64 + l];
        float  vr = (Pg + (size_t)base * 25)[1536 + l];
        float4 xv = ((const float4*)(xg + (size_t)base * 5))[l];
        float  xr = (xg + (size_t)base * 5)[256 + l];
        float2 av = ((const float2*)(ag + (size_t)base * 2))[l];
        float  y0 = Yg[base + l];
        float  y1 = Yg[N + base + l];

        // ---- 2) stage to LDS (coalesced layout) ----
        float4* s4 = (float4*)s;
        s4[0 * 64 + l] = v0; s4[1 * 64 + l] = v1; s4[2 * 64 + l] = v2;
        s4[3 * 64 + l] = v3; s4[4 * 64 + l] = v4; s4[5 * 64 + l] = v5;
        s[1536 + l] = vr;
        ((float4*)(s + 1600))[l] = xv;
        s[1856 + l] = xr;

        // ---- 3) transpose-read own item (same-wave DS ops are in-order;
        //         stride-25/5 = 2-way bank aliasing = free) ----
        const float* pr = s + l * 25;
        float p00 = pr[0],  p01 = pr[1],  p02 = pr[2];
        float p10 = pr[5],  p11 = pr[6],  p12 = pr[7];
        float p20 = pr[10], p21 = pr[11], p22 = pr[12];
        const float* xp = s + 1600 + l * 5;
        float x0 = xp[0], x1 = xp[1], x2 = xp[2];

        // ---- 4) EKF math ----
        float vel = g0 * av.x, angvel = g1 * av.y;

        float ar = x2 + angvel * dt + fPI;
        float w = fmodf(ar, f2PI);
        if (w < 0.0f) w += f2PI;
        float ang = w - fPI;

        float sn, cs;
        sincosf(ang, &sn, &cs);

        float px = fminf(fmaxf(x0 + vel * cs * dt, -1.0f), 1.0f);
        float py = fminf(fmaxf(x1 + vel * sn * dt, -1.0f), 1.0f);

        float m0 = -vel * sn * dt, m1 = vel * cs * dt;

        float b00 = p00 + m0 * p20, b01 = p01 + m0 * p21, b02 = p02 + m0 * p22;
        float b10 = p10 + m1 * p20, b11 = p11 + m1 * p21, b12 = p12 + m1 * p22;
        float t00 = b00 + m0 * b02, t01 = b01 + m1 * b02;
        float t10 = b10 + m0 * b12, t11 = b11 + m1 * b12;
        float t20 = p20 + m0 * p22, t21 = p21 + m1 * p22, t22 = p22;
        float t02 = b02, t12 = b12;

        t00 += q0; t11 += q1; t22 += q2;
        float s01 = 0.5f * (t01 + t10);
        float s02 = 0.5f * (t02 + t20);
        float s12 = 0.5f * (t12 + t21);
        t00 += EPS_; t11 += EPS_; t22 += EPS_;

        float S00 = q3 * og0 * og0 + vel * vel * e2k0 + e2s0;
        float S11 = q4 * og1 * og1 + angvel * angvel * e2k1 + e2s1;
        float K30 = q3 * og0 / S00;
        float K41 = q4 * og1 / S11;

        float xn3 = vel    + K30 * (y0 - og0 * vel);
        float xn4 = angvel + K41 * (y1 - og1 * angvel);
        float Pn33 = (1.0f - K30 * og0) * q3 + EPS_;
        float Pn44 = (1.0f - K41 * og1) * q4 + EPS_;

        // ---- 5) OUT layout into same slice (IN already consumed) ----
        float* xx = s + l * 5;
        xx[0] = px; xx[1] = py; xx[2] = ang; xx[3] = xn3; xx[4] = xn4;
        float* pp = s + 320 + l * 25;
        pp[0]  = t00; pp[1]  = s01; pp[2]  = s02; pp[3]  = 0.f; pp[4]  = 0.f;
        pp[5]  = s01; pp[6]  = t11; pp[7]  = s12; pp[8]  = 0.f; pp[9]  = 0.f;
        pp[10] = s02; pp[11] = s12; pp[12] = t22; pp[13] = 0.f; pp[14] = 0.f;
        pp[15] = 0.f; pp[16] = 0.f; pp[17] = 0.f; pp[18] = Pn33; pp[19] = 0.f;
        pp[20] = 0.f; pp[21] = 0.f; pp[22] = 0.f; pp[23] = 0.f; pp[24] = Pn44;
        float* kk = s + 1920 + l * 10;
        kk[0] = 0.f; kk[1] = 0.f; kk[2] = 0.f; kk[3] = 0.f; kk[4] = 0.f;
        kk[5] = 0.f; kk[6] = K30; kk[7] = 0.f; kk[8] = 0.f; kk[9] = K41;

        // ---- 6) coalesced stores: 12 dwordx4 per wave ----
        float4* gx4 = (float4*)(out + (size_t)base * 5);
        float4* gp4 = (float4*)(out + (size_t)5 * N + (size_t)base * 25);
        float4* gk4 = (float4*)(out + (size_t)30 * N + (size_t)base * 10);
        const float4* lx4 = (const float4*)s;
        const float4* lp4 = (const float4*)(s + 320);
        const float4* lk4 = (const float4*)(s + 1920);
        gx4[l] = lx4[l];
        if (l < 16) gx4[64 + l] = lx4[64 + l];
        #pragma unroll
        for (int j = 0; j < 6; ++j) gp4[j * 64 + l] = lp4[j * 64 + l];
        if (l < 16) gp4[384 + l] = lp4[384 + l];
        #pragma unroll
        for (int j = 0; j < 2; ++j) gk4[j * 64 + l] = lk4[j * 64 + l];
        if (l < 32) gk4[128 + l] = lk4[128 + l];
    } else {
        // Tail tile (global last, valid < 64): direct guarded scalar path.
        const int i = base + l;
        if (i < N) {
            const float* pr = Pg + (size_t)i * 25;
            float p00 = pr[0],  p01 = pr[1],  p02 = pr[2];
            float p10 = pr[5],  p11 = pr[6],  p12 = pr[7];
            float p20 = pr[10], p21 = pr[11], p22 = pr[12];
            float x0 = xg[i * 5 + 0], x1 = xg[i * 5 + 1], x2 = xg[i * 5 + 2];
            float a0 = ag[i * 2 + 0], a1 = ag[i * 2 + 1];
            float y0 = Yg[i], y1 = Yg[N + i];

            float vel = g0 * a0, angvel = g1 * a1;
            float ar = x2 + angvel * dt + fPI;
            float w = fmodf(ar, f2PI);
            if (w < 0.0f) w += f2PI;
            float ang = w - fPI;
            float sn, cs;
            sincosf(ang, &sn, &cs);
            float px = fminf(fmaxf(x0 + vel * cs * dt, -1.0f), 1.0f);
            float py = fminf(fmaxf(x1 + vel * sn * dt, -1.0f), 1.0f);
            float m0 = -vel * sn * dt, m1 = vel * cs * dt;
            float b00 = p00 + m0 * p20, b01 = p01 + m0 * p21, b02 = p02 + m0 * p22;
            float b10 = p10 + m1 * p20, b11 = p11 + m1 * p21, b12 = p12 + m1 * p22;
            float t00 = b00 + m0 * b02, t01 = b01 + m1 * b02;
            float t10 = b10 + m0 * b12, t11 = b11 + m1 * b12;
            float t20 = p20 + m0 * p22, t21 = p21 + m1 * p22, t22 = p22;
            float t02 = b02, t12 = b12;
            t00 += q0; t11 += q1; t22 += q2;
            float s01 = 0.5f * (t01 + t10);
            float s02 = 0.5f * (t02 + t20);
            float s12 = 0.5f * (t12 + t21);
            t00 += EPS_; t11 += EPS_; t22 += EPS_;
            float S00 = q3 * og0 * og0 + vel * vel * e2k0 + e2s0;
            float S11 = q4 * og1 * og1 + angvel * angvel * e2k1 + e2s1;
            float K30 = q3 * og0 / S00;
            float K41 = q4 * og1 / S11;
            float xn3 = vel    + K30 * (y0 - og0 * vel);
            float xn4 = angvel + K41 * (y1 - og1 * angvel);
            float Pn33 = (1.0f - K30 * og0) * q3 + EPS_;
            float Pn44 = (1.0f - K41 * og1) * q4 + EPS_;

            float* gx = out + (size_t)i * 5;
            gx[0] = px; gx[1] = py; gx[2] = ang; gx[3] = xn3; gx[4] = xn4;
            float* gp = out + (size_t)5 * N + (size_t)i * 25;
            gp[0] = t00; gp[1] = s01; gp[2] = s02; gp[3] = 0.f; gp[4] = 0.f;
            gp[5] = s01; gp[6] = t11; gp[7] = s12; gp[8] = 0.f; gp[9] = 0.f;
            gp[10] = s02; gp[11] = s12; gp[12] = t22; gp[13] = 0.f; gp[14] = 0.f;
            gp[15] = 0.f; gp[16] = 0.f; gp[17] = 0.f; gp[18] = Pn33; gp[19] = 0.f;
            gp[20] = 0.f; gp[21] = 0.f; gp[22] = 0.f; gp[23] = 0.f; gp[24] = Pn44;
            float* gk = out + (size_t)30 * N + (size_t)i * 10;
            gk[0] = 0.f; gk[1] = 0.f; gk[2] = 0.f; gk[3] = 0.f; gk[4] = 0.f;
            gk[5] = 0.f; gk[6] = K30; gk[7] = 0.f; gk[8] = 0.f; gk[9] = K41;
        }
    }
}

extern "C" void kernel_launch(void* const* d_in, const int* in_sizes, int n_in,
                              void* d_out, int out_size, void* d_ws, size_t ws_size,
                              hipStream_t stream) {
    const float* x     = (const float*)d_in[0];
    const float* P     = (const float*)d_in[1];
    const float* a     = (const float*)d_in[2];
    const float* Y     = (const float*)d_in[3];
    const float* n1    = (const float*)d_in[4];
    const float* n2s   = (const float*)d_in[5];
    const float* n2k   = (const float*)d_in[6];
    const float* gains = (const float*)d_in[7];
    const float* og    = (const float*)d_in[8];
    const int N = in_sizes[0] / 5;
    const int tiles = (N + BLK - 1) / BLK;
    const int G = (tiles + 3) / 4;   // 4 wave-tiles per 256-thr block
    ekf_kernel<<<G, 256, 0, stream>>>(x, P, a, Y, n1, n2s, n2k, gains, og,
                                      (float*)d_out, N);
}